// Round 6
// baseline (218.091 us; speedup 1.0000x reference)
//
#include <hip/hip_runtime.h>

typedef _Float16 f16;
typedef __attribute__((ext_vector_type(4))) _Float16 f16x4;
typedef __attribute__((ext_vector_type(8))) _Float16 f16x8;
typedef __attribute__((ext_vector_type(4))) float f32x4;

// Problem constants
#define D_DIM 256
#define K_CB  1024
#define N_TOT 32768
#define DHW   262144      // D*H*W per batch
#define ZQ_N  8388608
#define OUT_CODES 8388608
#define OUT_LOSS  8421376

// workspace layout (float offsets)
#define WS_BSP   0        // 1024*256 f16 = 131072 floats: Bhi[code][256]
#define WS_EN2   131072   // 1024 floats: -0.5*||e||^2
#define WS_CODES 132096   // 32768 ints
#define WS_CNT   164864   // 1 int
#define WS_LIST  164928   // 32768 ints (cap = all rows: safe-by-construction)
#define WS_RLOSS 197696   // 32768 floats: per-row ||z-e||^2
#define LIST_CAP 32768
#define EPS_GAP  0.08f    // ~9 sigma of the hi-only f16 gap error (std ~9e-3)

// ---------------------------------------------------------------------------
// prep: en2 = -0.5||e||^2 (fp32); Bhi[code][256] f16. grid 1024 x 64.
// ---------------------------------------------------------------------------
__global__ void vq_prep(const float* __restrict__ emb, float* __restrict__ ws) {
    const int k = blockIdx.x;
    const int t = threadIdx.x;
    const float4 v = *reinterpret_cast<const float4*>(emb + k * D_DIM + t * 4);
    float s = v.x * v.x + v.y * v.y + v.z * v.z + v.w * v.w;
#pragma unroll
    for (int off = 32; off > 0; off >>= 1) s += __shfl_down(s, off);
    if (t == 0) ws[WS_EN2 + k] = -0.5f * s;
    const float a[4] = {v.x, v.y, v.z, v.w};
    f16x4 hv;
#pragma unroll
    for (int i = 0; i < 4; ++i) hv[i] = (f16)a[i];
    *reinterpret_cast<f16x4*>(reinterpret_cast<f16*>(ws) + k * 256 + t * 4) = hv;
    if (k == 0 && t == 0) reinterpret_cast<int*>(ws + WS_CNT)[0] = 0;
}

// ---------------------------------------------------------------------------
// fused hi-only f16 MFMA distance-GEMM + argmax + per-row loss.
// grid 512 x 256.  Block: 64 rows x 1024 codes, K=256.
// Wave tile 64 rows x 64 cols (i=4 rowfrags x j=4 colfrags): 8 LDS reads per
// 16 MFMA (round-5 ratio was 7 per 12 -> LDS BW was the bottleneck).
// 16 q-iters = 4 code-tiles(256 cols) x 4 k-chunks(64).  B reg-prefetched.
// loss: ||z-e||^2 = ||z||^2 - 2*score, row norms from the A-stage.
// LDS: A 32K + Bs 32K + rowsum 1K = 65K -> 2 blocks/CU.
// ---------------------------------------------------------------------------
__global__ __launch_bounds__(256, 2) void vq_gemm(const float* __restrict__ z,
                                                  float* ws,
                                                  float* __restrict__ out) {
    __shared__ __align__(16) char lds[66560];
    f16* Ahi = reinterpret_cast<f16*>(lds);            // [64 r][256 k] swz
    f16* Bs  = reinterpret_cast<f16*>(lds + 32768);    // [256 c][64 k] swz
    float* rowsum = reinterpret_cast<float*>(lds + 65536);  // [4][64]
    float* comb = reinterpret_cast<float*>(lds + 32768);    // aliases Bs

    const f16* __restrict__ Bsp = reinterpret_cast<const f16*>(ws);
    const float* __restrict__ en2 = ws + WS_EN2;
    const int tid = threadIdx.x;
    const int lane = tid & 63;
    const int w = tid >> 6;                    // wave = col quadrant
    const int r0 = blockIdx.x * 64;
    const float* __restrict__ zb = z + (r0 >> 10) * DHW + (r0 & 1023);

    // ---- stage A once (f16 hi, XOR-swizzled) + row sq-norm partials ----
    {
        const int arow = tid & 63;             // lane = row -> coalesced
        const int adg  = tid >> 6;             // wave covers 64 d
        float sq = 0.f;
#pragma unroll
        for (int p = 0; p < 16; ++p) {
            const int d = adg * 64 + p * 4;
            f16x4 hv;
#pragma unroll
            for (int i = 0; i < 4; ++i) {
                const float x = zb[(d + i) * 1024 + arow];
                hv[i] = (f16)x;
                sq += x * x;
            }
            const int byte = (arow * 512 + d * 2) ^ ((arow & 7) << 4);
            *reinterpret_cast<f16x4*>(reinterpret_cast<char*>(Ahi) + byte) = hv;
        }
        rowsum[adg * 64 + arow] = sq;
    }

    float bv[16], sv[16];
    int   bk[16];
#pragma unroll
    for (int i = 0; i < 16; ++i) { bv[i] = -3.0e38f; sv[i] = -3.0e38f; bk[i] = 0; }

    f32x4 acc[4][4];
#pragma unroll
    for (int i = 0; i < 4; ++i)
#pragma unroll
        for (int j = 0; j < 4; ++j) acc[i][j] = f32x4{0.f, 0.f, 0.f, 0.f};

    // prologue: q=0 B tile into regs
    f16x8 breg[8];
#pragma unroll
    for (int p = 0; p < 8; ++p) {
        const int u = tid + p * 256;
        breg[p] = *reinterpret_cast<const f16x8*>(Bsp + (u >> 3) * 256 + (u & 7) * 8);
    }
    float e2v[4];

    for (int q = 0; q < 16; ++q) {
        __syncthreads();                       // prev Bs reads done
#pragma unroll
        for (int p = 0; p < 8; ++p) {
            const int u = tid + p * 256;
            const int col = u >> 3, k8 = (u & 7) * 8;
            const int byte = (col * 128 + k8 * 2) ^ ((col & 7) << 4);
            *reinterpret_cast<f16x8*>(reinterpret_cast<char*>(Bs) + byte) = breg[p];
        }
        if ((q & 3) == 2) {                    // en2 for next epilogue
            const int c0 = (q >> 2) * 256;
#pragma unroll
            for (int jf = 0; jf < 4; ++jf)
                e2v[jf] = en2[c0 + w * 64 + jf * 16 + (lane & 15)];
        }
        __syncthreads();                       // Bs visible
        if (q < 15) {                          // prefetch next tile (hides under MFMA)
            const int qn = q + 1;
            const int c0n = (qn >> 2) * 256, kbn = (qn & 3) * 64;
#pragma unroll
            for (int p = 0; p < 8; ++p) {
                const int u = tid + p * 256;
                breg[p] = *reinterpret_cast<const f16x8*>(
                    Bsp + (c0n + (u >> 3)) * 256 + kbn + (u & 7) * 8);
            }
        }
        const int kA = (q & 3) * 64;
#pragma unroll
        for (int s = 0; s < 2; ++s) {
            const int kl = s * 32 + (lane >> 4) * 8;
            f16x8 bf[4], af[4];
#pragma unroll
            for (int jf = 0; jf < 4; ++jf) {
                const int col = w * 64 + jf * 16 + (lane & 15);
                bf[jf] = *reinterpret_cast<const f16x8*>(
                    reinterpret_cast<const char*>(Bs) +
                    ((col * 128 + kl * 2) ^ ((col & 7) << 4)));
            }
#pragma unroll
            for (int i = 0; i < 4; ++i) {
                const int row = i * 16 + (lane & 15);
                af[i] = *reinterpret_cast<const f16x8*>(
                    reinterpret_cast<const char*>(Ahi) +
                    ((row * 512 + (kA + kl) * 2) ^ ((row & 7) << 4)));
            }
#pragma unroll
            for (int i = 0; i < 4; ++i)
#pragma unroll
                for (int jf = 0; jf < 4; ++jf)
                    acc[i][jf] = __builtin_amdgcn_mfma_f32_16x16x32_f16(
                        af[i], bf[jf], acc[i][jf], 0, 0, 0);
        }
        if ((q & 3) == 3) {                    // epilogue for code-tile q>>2
            const int c0 = (q >> 2) * 256;
#pragma unroll
            for (int jf = 0; jf < 4; ++jf) {
                const int col = c0 + w * 64 + jf * 16 + (lane & 15);
                const float e2 = e2v[jf];
#pragma unroll
                for (int i = 0; i < 4; ++i)
#pragma unroll
                    for (int r = 0; r < 4; ++r) {
                        const float v = acc[i][jf][r] + e2;
                        const int idx = i * 4 + r;
                        if (v > bv[idx]) { sv[idx] = bv[idx]; bv[idx] = v; bk[idx] = col; }
                        else if (v > sv[idx]) sv[idx] = v;
                    }
            }
#pragma unroll
            for (int i = 0; i < 4; ++i)
#pragma unroll
                for (int j = 0; j < 4; ++j) acc[i][j] = f32x4{0.f, 0.f, 0.f, 0.f};
        }
    }

    // butterfly across the 16 lanes sharing each row
#pragma unroll
    for (int m = 1; m <= 8; m <<= 1)
#pragma unroll
        for (int idx = 0; idx < 16; ++idx) {
            const float pv = __shfl_xor(bv[idx], m);
            const float ps = __shfl_xor(sv[idx], m);
            const int   pk = __shfl_xor(bk[idx], m);
            if (pv > bv[idx] || (pv == bv[idx] && pk < bk[idx])) {
                sv[idx] = fmaxf(bv[idx], ps);
                bv[idx] = pv; bk[idx] = pk;
            } else {
                sv[idx] = fmaxf(sv[idx], pv);
            }
        }

    __syncthreads();                           // Bs reads done; comb aliases Bs
    if ((lane & 15) == 0) {
#pragma unroll
        for (int idx = 0; idx < 16; ++idx) {
            const int row = (idx >> 2) * 16 + (lane >> 4) * 4 + (idx & 3);
            comb[(w * 64 + row) * 3 + 0] = bv[idx];
            comb[(w * 64 + row) * 3 + 1] = sv[idx];
            comb[(w * 64 + row) * 3 + 2] = __int_as_float(bk[idx]);
        }
    }
    __syncthreads();
    if (tid < 64) {
        const int row = tid;
        float bvf = comb[row * 3 + 0], svf = comb[row * 3 + 1];
        int   bkf = __float_as_int(comb[row * 3 + 2]);
#pragma unroll
        for (int q2 = 1; q2 < 4; ++q2) {
            const float v = comb[(q2 * 64 + row) * 3 + 0];
            const float s2 = comb[(q2 * 64 + row) * 3 + 1];
            const int   k2 = __float_as_int(comb[(q2 * 64 + row) * 3 + 2]);
            if (v > bvf) { svf = fmaxf(bvf, s2); bvf = v; bkf = k2; }
            else         { svf = fmaxf(svf, v); }
        }
        const int n = r0 + row;
        reinterpret_cast<int*>(ws + WS_CODES)[n] = bkf;
        out[OUT_CODES + n] = (float)bkf;
        const float znorm = rowsum[row] + rowsum[64 + row] +
                            rowsum[128 + row] + rowsum[192 + row];
        ws[WS_RLOSS + n] = znorm - 2.f * bvf;  // ||z-e||^2 (f16-accurate)
        if (bvf - svf < EPS_GAP) {
            const int pos = atomicAdd(reinterpret_cast<int*>(ws + WS_CNT), 1);
            if (pos < LIST_CAP) reinterpret_cast<int*>(ws + WS_LIST)[pos] = n;
        }
    }
}

// ---------------------------------------------------------------------------
// exact fp32 rescore of near-tie rows (expected ~500). grid 256 x 256.
// Also rewrites the row's exact loss entry.
// ---------------------------------------------------------------------------
__global__ __launch_bounds__(256) void vq_rescore(const float* __restrict__ z,
                                                  const float* __restrict__ emb,
                                                  float* ws,
                                                  float* __restrict__ out) {
    __shared__ float zl[256];
    __shared__ float zred[4];
    __shared__ float rv[4];
    __shared__ int   rk[4];
    const int cnt0 = reinterpret_cast<const int*>(ws + WS_CNT)[0];
    const int cnt = cnt0 < LIST_CAP ? cnt0 : LIST_CAP;
    const int t = threadIdx.x;
    for (int it = blockIdx.x; it < cnt; it += gridDim.x) {
        const int n = reinterpret_cast<const int*>(ws + WS_LIST)[it];
        const int b = n >> 10, hw = n & 1023;
        __syncthreads();                       // protect zl/zred reuse
        const float x = z[b * DHW + t * 1024 + hw];
        zl[t] = x;
        float zs = x * x;
#pragma unroll
        for (int off = 32; off > 0; off >>= 1) zs += __shfl_down(zs, off);
        if ((t & 63) == 0) zred[t >> 6] = zs;
        __syncthreads();
        float bvv = -3.0e38f; int bkk = 0;
#pragma unroll
        for (int j = 0; j < 4; ++j) {
            const int k = t + j * 256;
            const float* e = emb + k * D_DIM;
            float dot = 0.f;
#pragma unroll 8
            for (int d = 0; d < 256; d += 4) {
                const float4 ev = *reinterpret_cast<const float4*>(e + d);
                const float4 zv = *reinterpret_cast<const float4*>(zl + d);
                dot += ev.x * zv.x + ev.y * zv.y + ev.z * zv.z + ev.w * zv.w;
            }
            const float v = dot + ws[WS_EN2 + k];
            if (v > bvv || (v == bvv && k < bkk)) { bvv = v; bkk = k; }
        }
#pragma unroll
        for (int m = 1; m <= 32; m <<= 1) {
            const float pv = __shfl_xor(bvv, m);
            const int   pk = __shfl_xor(bkk, m);
            if (pv > bvv || (pv == bvv && pk < bkk)) { bvv = pv; bkk = pk; }
        }
        if ((t & 63) == 0) { rv[t >> 6] = bvv; rk[t >> 6] = bkk; }
        __syncthreads();
        if (t == 0) {
#pragma unroll
            for (int q = 1; q < 4; ++q)
                if (rv[q] > bvv || (rv[q] == bvv && rk[q] < bkk)) { bvv = rv[q]; bkk = rk[q]; }
            reinterpret_cast<int*>(ws + WS_CODES)[n] = bkk;
            out[OUT_CODES + n] = (float)bkk;
            const float znorm = zred[0] + zred[1] + zred[2] + zred[3];
            ws[WS_RLOSS + n] = znorm - 2.f * bvv;
        }
    }
}

// ---------------------------------------------------------------------------
// gather z_q = embedding[codes] (no z read, no loss - loss lives in RLOSS).
// grid 512 x 256: block = 64 spatial positions x 256 d.
// ---------------------------------------------------------------------------
__global__ __launch_bounds__(256) void vq_gather(const float* __restrict__ emb,
                                                 float* ws,
                                                 float* __restrict__ out) {
    __shared__ __align__(16) float el[64][260];   // 1040B rows: 16B-aligned
    __shared__ int cl[64];
    const int tid = threadIdx.x;
    const int n0 = blockIdx.x * 64;
    const int b = n0 >> 10, hw0 = n0 & 1023;
    if (tid < 64) cl[tid] = reinterpret_cast<const int*>(ws + WS_CODES)[n0 + tid];
    __syncthreads();
#pragma unroll
    for (int p = 0; p < 16; ++p) {
        const int u = tid + p * 256;
        const int r = u >> 6, f4 = (u & 63) * 4;
        *reinterpret_cast<float4*>(&el[r][f4]) =
            *reinterpret_cast<const float4*>(emb + cl[r] * D_DIM + f4);
    }
    __syncthreads();
    const int hw4 = (tid & 15) * 4, dg = tid >> 4;   // dg: 16 d each
    float* op = out + b * DHW + hw0 + hw4;
#pragma unroll
    for (int dd = 0; dd < 16; ++dd) {
        const int d = dg * 16 + dd;
        float4 q;
        q.x = el[hw4 + 0][d]; q.y = el[hw4 + 1][d];
        q.z = el[hw4 + 2][d]; q.w = el[hw4 + 3][d];
        *reinterpret_cast<float4*>(op + d * 1024) = q;
    }
}

// ---------------------------------------------------------------------------
// finalize: loss = 1.25 * sum(RLOSS) / 8388608. 1 block x 256 threads.
// ---------------------------------------------------------------------------
__global__ __launch_bounds__(256) void vq_finalize(const float* __restrict__ ws,
                                                   float* __restrict__ out) {
    __shared__ float red[4];
    const int t = threadIdx.x;
    const float4* rl = reinterpret_cast<const float4*>(ws + WS_RLOSS);
    float s = 0.f;
#pragma unroll
    for (int i = 0; i < 32; ++i) {
        const float4 v = rl[t + i * 256];
        s += v.x + v.y + v.z + v.w;
    }
#pragma unroll
    for (int off = 32; off > 0; off >>= 1) s += __shfl_down(s, off);
    if ((t & 63) == 0) red[t >> 6] = s;
    __syncthreads();
    if (t == 0)
        out[OUT_LOSS] = (red[0] + red[1] + red[2] + red[3]) * (1.25f / 8388608.0f);
}

// ---------------------------------------------------------------------------
extern "C" void kernel_launch(void* const* d_in, const int* in_sizes, int n_in,
                              void* d_out, int out_size, void* d_ws, size_t ws_size,
                              hipStream_t stream) {
    const float* z   = (const float*)d_in[0];   // (32,256,32,32)
    const float* emb = (const float*)d_in[1];   // (1024,256)
    float* out = (float*)d_out;
    float* ws  = (float*)d_ws;

    vq_prep<<<K_CB, 64, 0, stream>>>(emb, ws);
    vq_gemm<<<N_TOT / 64, 256, 0, stream>>>(z, ws, out);
    vq_rescore<<<256, 256, 0, stream>>>(z, emb, ws, out);
    vq_gather<<<ZQ_N / (256 * 64), 256, 0, stream>>>(emb, ws, out);
    vq_finalize<<<1, 256, 0, stream>>>(ws, out);
}